// Round 14
// baseline (106.873 us; speedup 1.0000x reference)
//
#include <hip/hip_runtime.h>
#include <math.h>

// GptOssRouter: T=16384, H=2880, E=128, K=4.
// K0: pre-split w (fp32 -> bf16 h/l, trunc-exact) into d_ws as 32-k MFMA
//     B-fragment tiles: tile(F,c32,p)[lane] = 8 bf16 of
//     w[F*16+(lane&15)][c32*32+(lane>>4)*8 ...].
// K1 (fused): BARRIER-FREE K-loop. 32 tokens x 128 experts per block,
//     grid=512, NT=512, 2 blocks/CU. 8 waves = 2 expert-halves x 4 k-quarters;
//     each wave: 32 tok x 64 exp over ~720 k. Both operands register-direct:
//     w frags from wp (L2), x A-frags straight from global (2 dwordx4/frag),
//     h/l split IN REGISTERS. No __syncthreads in the K-loop -> no vmcnt(0)
//     barrier drains; compiler pipelines freely. Epilogue: cross-kq LDS
//     reduction, stripe-top8 + certified-gap (TAU=2.5e-4): fast fp32 softmax;
//     rare fp64 rescore (order == float64 numpy reference).

#define T_TOK 16384
#define HDIM  2880
#define EEXP  128
#define KTOP  4

#define TM    32
#define NT    512
#define TAU   2.5e-4f

// LDS layout (bytes):
#define PART_OFF   0           // [3][32][132] f32 partials = 50688
#define LOGIT_OFF  50688       // [32][130] f32 = 16640
#define CVF_OFF    67328       // [32][8] f32
#define CIE_OFF    68352       // [32][8] i32
#define FLG_OFF    69376       // [32] i32
#define SVD_OFF    69504       // [32][4] f64
#define SID_OFF    70528       // [32][4] i32
#define CVD_OFF    71040       // [8] f64
#define SMEM_SZ    71104

typedef __attribute__((ext_vector_type(8))) short bf16x8;
typedef __attribute__((ext_vector_type(4))) float f32x4;

#define MFMA(a, b, c) __builtin_amdgcn_mfma_f32_16x16x32_bf16((a), (b), (c), 0, 0, 0)

// ---------------- K0: w pre-split into 32-k fragment tiles ------------------
__global__ __launch_bounds__(256) void w_split(
    const float* __restrict__ w, char* __restrict__ wp)
{
    const int gid  = blockIdx.x * 256 + threadIdx.x;   // 46080 = 720 tiles * 64
    const int lane = gid & 63;
    const int q    = gid >> 6;        // 0..719
    const int c32  = q % 90;
    const int F    = q / 90;          // 0..7
    const int e    = F * 16 + (lane & 15);
    const int k0   = c32 * 32 + (lane >> 4) * 8;

    const float* src = w + (size_t)e * HDIM + k0;
    float4 v0 = *(const float4*)(src);
    float4 v1 = *(const float4*)(src + 4);
    float vv[8] = {v0.x, v0.y, v0.z, v0.w, v1.x, v1.y, v1.z, v1.w};
    union { unsigned short s[8]; uint4 u; } H, L;
#pragma unroll
    for (int j = 0; j < 8; ++j) {
        unsigned u = __float_as_uint(vv[j]);
        H.s[j] = (unsigned short)(u >> 16);
        float rr = vv[j] - __uint_as_float(u & 0xffff0000u);
        L.s[j] = (unsigned short)(__float_as_uint(rr) >> 16);
    }
    const int tile = (F * 90 + c32) * 2;               // h; l at +1
    *(uint4*)(wp + (size_t)tile * 1024 + lane * 16)       = H.u;
    *(uint4*)(wp + (size_t)(tile + 1) * 1024 + lane * 16) = L.u;
}

// in-register split: 8 floats -> h bf16x8 (trunc) + l bf16x8 (trunc of resid)
static __device__ __forceinline__ void split8(float4 v0, float4 v1,
                                              bf16x8* h8, bf16x8* l8) {
    union { float4 f; unsigned u[4]; } a, b; a.f = v0; b.f = v1;
    union { unsigned u[4]; bf16x8 v; } H, L;
    H.u[0] = __builtin_amdgcn_perm(a.u[1], a.u[0], 0x07060302u);
    H.u[1] = __builtin_amdgcn_perm(a.u[3], a.u[2], 0x07060302u);
    H.u[2] = __builtin_amdgcn_perm(b.u[1], b.u[0], 0x07060302u);
    H.u[3] = __builtin_amdgcn_perm(b.u[3], b.u[2], 0x07060302u);
    float r0 = v0.x - __uint_as_float(a.u[0] & 0xffff0000u);
    float r1 = v0.y - __uint_as_float(a.u[1] & 0xffff0000u);
    float r2 = v0.z - __uint_as_float(a.u[2] & 0xffff0000u);
    float r3 = v0.w - __uint_as_float(a.u[3] & 0xffff0000u);
    float r4 = v1.x - __uint_as_float(b.u[0] & 0xffff0000u);
    float r5 = v1.y - __uint_as_float(b.u[1] & 0xffff0000u);
    float r6 = v1.z - __uint_as_float(b.u[2] & 0xffff0000u);
    float r7 = v1.w - __uint_as_float(b.u[3] & 0xffff0000u);
    L.u[0] = __builtin_amdgcn_perm(__float_as_uint(r1), __float_as_uint(r0), 0x07060302u);
    L.u[1] = __builtin_amdgcn_perm(__float_as_uint(r3), __float_as_uint(r2), 0x07060302u);
    L.u[2] = __builtin_amdgcn_perm(__float_as_uint(r5), __float_as_uint(r4), 0x07060302u);
    L.u[3] = __builtin_amdgcn_perm(__float_as_uint(r7), __float_as_uint(r6), 0x07060302u);
    *h8 = H.v; *l8 = L.v;
}

// ---------------- K1: fused GEMM + selection --------------------------------
__global__ __launch_bounds__(NT, 4) void router_fused(
    const float* __restrict__ x, const char* __restrict__ wp,
    const float* __restrict__ w, const float* __restrict__ bias,
    float* __restrict__ out)
{
    __shared__ char smem[SMEM_SZ];
    const int tid  = threadIdx.x;
    const int tok0 = blockIdx.x * TM;
    const int lane = tid & 63;
    const int wv   = tid >> 6;          // 0..7
    const int eh   = wv & 1;            // expert half
    const int kq   = wv >> 1;           // k-quarter 0..3
    const int r    = lane & 15;
    const int g    = lane >> 4;

    // chunk range for this k-quarter: counts {23,23,22,22}
    const int c0 = (kq < 2) ? kq * 23 : 46 + (kq - 2) * 22;
    const int c1 = c0 + ((kq < 2) ? 23 : 22);

    // x row pointers for the two token fragments
    const float* xp0 = x + (size_t)(tok0 + r) * HDIM + g * 8;
    const float* xp1 = x + (size_t)(tok0 + 16 + r) * HDIM + g * 8;
    // w fragment base: addr = wbase + F*184320 + c*2048 + p*1024
    const char* wbase = wp + lane * 16 + (size_t)(eh * 4) * 184320;

    f32x4 acc[2][4];
    const f32x4 zf = {0.f, 0.f, 0.f, 0.f};
#pragma unroll
    for (int tf = 0; tf < 2; ++tf)
#pragma unroll
        for (int ct = 0; ct < 4; ++ct) acc[tf][ct] = zf;

#define LOADX(X, cc) do { int k_ = (cc) * 32;                         \
        X[0] = *(const float4*)(xp0 + k_);                            \
        X[1] = *(const float4*)(xp0 + k_ + 4);                        \
        X[2] = *(const float4*)(xp1 + k_);                            \
        X[3] = *(const float4*)(xp1 + k_ + 4); } while (0)

#define COMPUTE(X, cc) do {                                           \
        bf16x8 ah0, al0, ah1, al1;                                    \
        split8(X[0], X[1], &ah0, &al0);                               \
        split8(X[2], X[3], &ah1, &al1);                               \
        const char* wc_ = wbase + (cc) * 2048;                        \
        _Pragma("unroll")                                             \
        for (int ct_ = 0; ct_ < 4; ++ct_) {                           \
            bf16x8 bh = *(const bf16x8*)(wc_ + ct_ * 184320);         \
            bf16x8 bl = *(const bf16x8*)(wc_ + ct_ * 184320 + 1024);  \
            acc[0][ct_] = MFMA(ah0, bh, acc[0][ct_]);                 \
            acc[1][ct_] = MFMA(ah1, bh, acc[1][ct_]);                 \
            acc[0][ct_] = MFMA(ah0, bl, acc[0][ct_]);                 \
            acc[1][ct_] = MFMA(ah1, bl, acc[1][ct_]);                 \
            acc[0][ct_] = MFMA(al0, bh, acc[0][ct_]);                 \
            acc[1][ct_] = MFMA(al1, bh, acc[1][ct_]);                 \
        } } while (0)

    float4 xA[4], xB[4];
    LOADX(xA, c0);
    int c = c0;
    while (c + 1 < c1) {
        LOADX(xB, c + 1);
        COMPUTE(xA, c);
        if (c + 2 < c1) LOADX(xA, c + 2);
        COMPUTE(xB, c + 1);
        c += 2;
    }
    if (c < c1) COMPUTE(xA, c);

    // -------- cross-kq reduction --------------------------------------------
    float* part = (float*)smem;          // [3][32][132]
    if (kq != 0) {
        const int pb = (kq - 1) * 4224;
#pragma unroll
        for (int tf = 0; tf < 2; ++tf)
#pragma unroll
        for (int ct = 0; ct < 4; ++ct)
#pragma unroll
        for (int q = 0; q < 4; ++q) {
            int tok = tf * 16 + g * 4 + q;
            int e   = eh * 64 + ct * 16 + r;
            part[pb + tok * 132 + e] = acc[tf][ct][q];
        }
    }
    __syncthreads();

    float* logitsL = (float*)(smem + LOGIT_OFF);
    if (kq == 0) {
#pragma unroll
        for (int tf = 0; tf < 2; ++tf)
#pragma unroll
        for (int ct = 0; ct < 4; ++ct) {
            int e = eh * 64 + ct * 16 + r;
            float bv = bias[e];
#pragma unroll
            for (int q = 0; q < 4; ++q) {
                int tok = tf * 16 + g * 4 + q;
                float s = acc[tf][ct][q] + bv
                        + part[0 * 4224 + tok * 132 + e]
                        + part[1 * 4224 + tok * 132 + e]
                        + part[2 * 4224 + tok * 132 + e];
                logitsL[tok * 130 + e] = s;
            }
        }
    }
    float*  cvf = (float*) (smem + CVF_OFF);
    int*    cie = (int*)   (smem + CIE_OFF);
    int*    flg = (int*)   (smem + FLG_OFF);
    double* svd = (double*)(smem + SVD_OFF);
    int*    sid = (int*)   (smem + SID_OFF);
    double* cvd = (double*)(smem + CVD_OFF);
    __syncthreads();

    // -------- stripe top-8: threads 0-255, (t, s) scans 16 experts ----------
    if (tid < 256) {
        const int t = tid >> 3, s = tid & 7;
        float v[8]; int id[8];
#pragma unroll
        for (int k = 0; k < 8; ++k) { v[k] = -3.4e38f; id[k] = 0x7fffffff; }
        for (int jj = 0; jj < 16; ++jj) {
            float lv = logitsL[t * 130 + s * 16 + jj];
            int   e  = s * 16 + jj;
            bool gt[8];
#pragma unroll
            for (int k = 0; k < 8; ++k)
                gt[k] = (lv > v[k]) || (lv == v[k] && e < id[k]);
#pragma unroll
            for (int k = 7; k >= 1; --k)
                if (gt[k - 1]) { v[k] = v[k - 1]; id[k] = id[k - 1]; }
#pragma unroll
            for (int k = 0; k < 8; ++k) {
                bool put = gt[k] && (k == 0 || !gt[k - 1]);
                if (put) { v[k] = lv; id[k] = e; }
            }
        }
#pragma unroll
        for (int rd = 0; rd < 8; ++rd) {
            float hv = v[0]; int hi = id[0];
#pragma unroll
            for (int off = 1; off < 8; off <<= 1) {
                float ov = __shfl_xor(hv, off);
                int   oi = __shfl_xor(hi, off);
                if (ov > hv || (ov == hv && oi < hi)) { hv = ov; hi = oi; }
            }
            if (s == 0) { cvf[t * 8 + rd] = hv; cie[t * 8 + rd] = hi; }
            bool mine = (v[0] == hv) && (id[0] == hi);
            if (mine) {
#pragma unroll
                for (int k = 0; k < 7; ++k) { v[k] = v[k + 1]; id[k] = id[k + 1]; }
                v[7] = -3.4e38f; id[7] = 0x7fffffff;
            }
        }
    }
    __syncthreads();

    // -------- certified-gap test + fast-path fill ---------------------------
    if (tid < TM) {
        float gmin = 3.4e38f;
#pragma unroll
        for (int k = 0; k < 4; ++k)
            gmin = fminf(gmin, cvf[tid * 8 + k] - cvf[tid * 8 + k + 1]);
        flg[tid] = (gmin < TAU);
    }
    if (tid < 128) {
        int t2 = tid >> 2, k = tid & 3;
        svd[t2 * 4 + k] = (double)cvf[t2 * 8 + k];
        sid[t2 * 4 + k] = cie[t2 * 8 + k];
    }
    __syncthreads();

    // -------- rare slow path: fp64 rescore (1 candidate per wave) -----------
    for (int ts = 0; ts < TM; ++ts) {
        if (!flg[ts]) continue;              // uniform across block
        {
            const int ce = cie[ts * 8 + wv];
            const float4* xr = (const float4*)(x + (size_t)(tok0 + ts) * HDIM);
            const float4* wr = (const float4*)(w + (size_t)ce * HDIM);
            double q0 = 0.0, q1 = 0.0, q2 = 0.0, q3 = 0.0;
            for (int i2 = 0; i2 < 12; ++i2) {
                int fi = lane + i2 * 64;
                if (fi < HDIM / 4) {
                    float4 xv = xr[fi];
                    float4 wv4 = wr[fi];
                    q0 = fma((double)xv.x, (double)wv4.x, q0);
                    q1 = fma((double)xv.y, (double)wv4.y, q1);
                    q2 = fma((double)xv.z, (double)wv4.z, q2);
                    q3 = fma((double)xv.w, (double)wv4.w, q3);
                }
            }
            double accd = (q0 + q2) + (q1 + q3);
#pragma unroll
            for (int off = 32; off > 0; off >>= 1)
                accd += __shfl_xor(accd, off);
            if (lane == 0) cvd[wv] = accd + (double)bias[ce];
        }
        __syncthreads();
        if (tid < 8) {                        // fp64 rank among 8 candidates
            double mv = cvd[tid]; int mi2 = cie[ts * 8 + tid];
            int rk = 0;
#pragma unroll
            for (int j2 = 0; j2 < 8; ++j2) {
                double oj = cvd[j2];
                rk += (oj > mv) || (oj == mv && cie[ts * 8 + j2] < mi2);
            }
            if (rk < 4) { svd[ts * 4 + rk] = mv; sid[ts * 4 + rk] = mi2; }
        }
        __syncthreads();
    }

    // -------- softmax + outputs ---------------------------------------------
    float* srow = (float*)smem;              // [32][128], overlays dead part
    float4 z4 = make_float4(0.f, 0.f, 0.f, 0.f);
#pragma unroll
    for (int i = 0; i < 2; ++i)
        ((float4*)srow)[tid + i * NT] = z4;
    __syncthreads();

    if (tid < TM) {
        double m  = svd[tid * 4];
        double e0 = exp(svd[tid * 4 + 0] - m), e1 = exp(svd[tid * 4 + 1] - m);
        double e2 = exp(svd[tid * 4 + 2] - m), e3 = exp(svd[tid * 4 + 3] - m);
        double inv = 1.0 / ((e0 + e1) + (e2 + e3));
        float* oidx = out + (size_t)T_TOK * EEXP + (size_t)(tok0 + tid) * KTOP;
        int i0 = sid[tid * 4 + 0], i1 = sid[tid * 4 + 1];
        int i2 = sid[tid * 4 + 2], i3 = sid[tid * 4 + 3];
        oidx[0] = (float)i0; oidx[1] = (float)i1;
        oidx[2] = (float)i2; oidx[3] = (float)i3;
        srow[tid * EEXP + i0] = (float)(e0 * inv);
        srow[tid * EEXP + i1] = (float)(e1 * inv);
        srow[tid * EEXP + i2] = (float)(e2 * inv);
        srow[tid * EEXP + i3] = (float)(e3 * inv);
    }
    __syncthreads();

    float4* orow = (float4*)(out + (size_t)tok0 * EEXP);
#pragma unroll
    for (int i = 0; i < 2; ++i)
        orow[tid + i * NT] = ((float4*)srow)[tid + i * NT];
}

extern "C" void kernel_launch(void* const* d_in, const int* in_sizes, int n_in,
                              void* d_out, int out_size, void* d_ws, size_t ws_size,
                              hipStream_t stream) {
    const float* x    = (const float*)d_in[0];
    const float* w    = (const float*)d_in[1];
    const float* bias = (const float*)d_in[2];
    float* out        = (float*)d_out;
    char*  wp         = (char*)d_ws;   // 1440 KiB (8*90*2 tiles * 1KB)

    hipLaunchKernelGGL(w_split, dim3(180), dim3(256), 0, stream, w, wp);
    hipLaunchKernelGGL(router_fused, dim3(T_TOK / TM), dim3(NT), 0, stream,
                       x, wp, w, bias, out);
}

// Round 15
// 80.583 us; speedup vs baseline: 1.3262x; 1.3262x over previous
//
#include <hip/hip_runtime.h>
#include <math.h>

// GptOssRouter: T=16384, H=2880, E=128, K=4.
// K0: pre-split w (fp32 -> bf16 h/l, trunc-exact) into d_ws as MFMA B-frag
//     tiles. K1: 32 tok x 128 exp per block, grid=512, depth-3 reg/LDS
//     pipeline. KEY CHANGE vs r12: K-loop barriers are raw s_barrier with
//     counted-wait discipline (lgkmcnt(0) only; NO vmcnt(0) drain), so the
//     depth-3 x prefetch and depth-2 w prefetch stay in flight across
//     barriers (T4). Math: 3-pass split-bf16 MFMA xh*wh+xh*wl+xl*wh
//     (err ~1e-5); fused stripe-top8 + certified-gap (TAU=2.5e-4) ->
//     fast fp32 softmax; rare fp64 rescore (order == float64 numpy ref).

#define T_TOK 16384
#define HDIM  2880
#define EEXP  128
#define KTOP  4

#define TM   32
#define NT   256
#define KC   64
#define NCH  (HDIM / KC)     // 45 = 15 * 3
#define XBUF 8192            // 32 rows * 256 B
#define TAU  2.5e-4f

typedef __attribute__((ext_vector_type(8))) short bf16x8;
typedef __attribute__((ext_vector_type(4))) float f32x4;

#define MFMA(a, b, c) __builtin_amdgcn_mfma_f32_16x16x32_bf16((a), (b), (c), 0, 0, 0)

// K-loop barrier: wait LDS ops only (NO vmcnt drain), raw s_barrier,
// compiler memory fences on both sides so nothing crosses.
#define SYNCK() do {                                              \
        asm volatile("s_waitcnt lgkmcnt(0)" ::: "memory");        \
        __builtin_amdgcn_s_barrier();                             \
        asm volatile("" ::: "memory");                            \
    } while (0)

// ---------------- K0: w pre-split into fragment-tiled bf16 h/l -------------
__global__ __launch_bounds__(256) void w_split(
    const float* __restrict__ w, char* __restrict__ wp)
{
    const int gid  = blockIdx.x * 256 + threadIdx.x;   // 46080 total
    const int lane = gid & 63;
    const int q    = gid >> 6;        // 0..719
    const int ks   = q & 1;
    const int q2   = q >> 1;          // 0..359
    const int c    = q2 % NCH;
    const int F    = q2 / NCH;        // 0..7
    const int e    = F * 16 + (lane & 15);
    const int k0   = c * 64 + ks * 32 + (lane >> 4) * 8;

    const float* src = w + (size_t)e * HDIM + k0;
    float4 v0 = *(const float4*)(src);
    float4 v1 = *(const float4*)(src + 4);
    float vv[8] = {v0.x, v0.y, v0.z, v0.w, v1.x, v1.y, v1.z, v1.w};
    union { unsigned short s[8]; uint4 u; } H, L;
#pragma unroll
    for (int j = 0; j < 8; ++j) {
        unsigned u = __float_as_uint(vv[j]);
        H.s[j] = (unsigned short)(u >> 16);
        float rr = vv[j] - __uint_as_float(u & 0xffff0000u);
        L.s[j] = (unsigned short)(__float_as_uint(rr) >> 16);
    }
    const int tile = ((F * NCH + c) * 2 + ks) * 2;     // p=0 (h); l at +1
    *(uint4*)(wp + (size_t)tile * 1024 + lane * 16)       = H.u;
    *(uint4*)(wp + (size_t)(tile + 1) * 1024 + lane * 16) = L.u;
}

// x split: v = h + l (h = trunc_bf16(v), l = trunc_bf16(v - h), both exact);
// h 8B at swizzled slot, l at +128 within the 256B row.
static __device__ __forceinline__ void split_write256(char* base, int off, float4 v) {
    union { float4 v4; unsigned u[4]; } uv; uv.v4 = v;
    unsigned h01 = __builtin_amdgcn_perm(uv.u[1], uv.u[0], 0x07060302u);
    unsigned h23 = __builtin_amdgcn_perm(uv.u[3], uv.u[2], 0x07060302u);
    float r0 = v.x - __uint_as_float(uv.u[0] & 0xffff0000u);
    float r1 = v.y - __uint_as_float(uv.u[1] & 0xffff0000u);
    float r2 = v.z - __uint_as_float(uv.u[2] & 0xffff0000u);
    float r3 = v.w - __uint_as_float(uv.u[3] & 0xffff0000u);
    unsigned l01 = __builtin_amdgcn_perm(__float_as_uint(r1), __float_as_uint(r0), 0x07060302u);
    unsigned l23 = __builtin_amdgcn_perm(__float_as_uint(r3), __float_as_uint(r2), 0x07060302u);
    uint2 hw; hw.x = h01; hw.y = h23;
    uint2 lw; lw.x = l01; lw.y = l23;
    *(uint2*)(base + off)       = hw;
    *(uint2*)(base + off + 128) = lw;
}

// ---------------- K1: fused GEMM + selection --------------------------------
__global__ __launch_bounds__(NT, 2) void router_fused(
    const float* __restrict__ x, const char* __restrict__ wp,
    const float* __restrict__ w, const float* __restrict__ bias,
    float* __restrict__ out)
{
    __shared__ char smem[3 * XBUF];     // 24576 B
    const int tid  = threadIdx.x;
    const int tok0 = blockIdx.x * TM;
    const int lane = tid & 63;
    const int wv   = tid >> 6;          // expert 32-group 0..3
    const int r    = lane & 15;
    const int g    = lane >> 4;

    char* xb0 = smem;
    char* xb1 = smem + XBUF;
    char* xb2 = smem + 2 * XBUF;

    // x staging map: 512 float4 / 256 thr = 2 per thread
    int xoff[2];
    const float* xptr[2];
#pragma unroll
    for (int i = 0; i < 2; ++i) {
        int f = tid + i * NT;
        int row = f >> 4, c4 = f & 15;
        xoff[i] = row * 256 + ((((c4 >> 1) ^ (row & 7)) << 4) | ((c4 & 1) << 3));
        xptr[i] = x + (size_t)(tok0 + row) * HDIM + c4 * 4;
    }

    // a-frag read offsets: [tokfrag][ks]
    int aoff[2][2];
#pragma unroll
    for (int tf = 0; tf < 2; ++tf) {
        int row = tf * 16 + r;
#pragma unroll
        for (int ks = 0; ks < 2; ++ks)
            aoff[tf][ks] = row * 256 + (((ks * 4 + g) ^ (row & 7)) << 4);
    }

    f32x4 a00 = {0.f, 0.f, 0.f, 0.f}, a01 = a00, a10 = a00, a11 = a00;

#define LOADX(pf, cc) do {                                            \
        pf[0] = *(const float4*)(xptr[0] + (cc) * KC);                \
        pf[1] = *(const float4*)(xptr[1] + (cc) * KC); } while (0)

#define WRITEX(pf, bb) do {                                           \
        split_write256((bb), xoff[0], pf[0]);                         \
        split_write256((bb), xoff[1], pf[1]); } while (0)

    // w frag tiles: idx = F2*4 + ks*2 + p
#define LOADW(W, cc) do {                                             \
        _Pragma("unroll")                                             \
        for (int F2 = 0; F2 < 2; ++F2)                                \
        _Pragma("unroll")                                             \
        for (int ks_ = 0; ks_ < 2; ++ks_)                             \
        _Pragma("unroll")                                             \
        for (int p_ = 0; p_ < 2; ++p_)                                \
            W[F2*4 + ks_*2 + p_] = *(const bf16x8*)(wp +              \
                (size_t)((((wv*2 + F2) * NCH + (cc)) * 2 + ks_) * 2 + p_) * 1024 \
                + lane * 16); } while (0)

#define MFMA_CHUNK(cb, W) do {                                        \
        _Pragma("unroll")                                             \
        for (int ks_ = 0; ks_ < 2; ++ks_) {                           \
            bf16x8 ah0 = *(const bf16x8*)((cb) + aoff[0][ks_]);       \
            bf16x8 al0 = *(const bf16x8*)((cb) + aoff[0][ks_] + 128); \
            bf16x8 ah1 = *(const bf16x8*)((cb) + aoff[1][ks_]);       \
            bf16x8 al1 = *(const bf16x8*)((cb) + aoff[1][ks_] + 128); \
            bf16x8 bh0 = W[ks_*2],     bl0 = W[ks_*2 + 1];            \
            bf16x8 bh1 = W[4 + ks_*2], bl1 = W[4 + ks_*2 + 1];        \
            a00 = MFMA(ah0, bh0, a00); a01 = MFMA(ah0, bh1, a01);     \
            a10 = MFMA(ah1, bh0, a10); a11 = MFMA(ah1, bh1, a11);     \
            a00 = MFMA(ah0, bl0, a00); a01 = MFMA(ah0, bl1, a01);     \
            a10 = MFMA(ah1, bl0, a10); a11 = MFMA(ah1, bl1, a11);     \
            a00 = MFMA(al0, bh0, a00); a01 = MFMA(al0, bh1, a01);     \
            a10 = MFMA(al1, bh0, a10); a11 = MFMA(al1, bh1, a11);     \
        } } while (0)

    float4 pfA[2], pfB[2], pfC[2];
    bf16x8 wA[8], wB[8], wC[8];

    // prologue: chunks 0..2 in regs, chunk 0 -> xb0; w chunks 0,1 in regs
    LOADX(pfA, 0); LOADX(pfB, 1); LOADX(pfC, 2);
    LOADW(wA, 0); LOADW(wB, 1);
    WRITEX(pfA, xb0);
    SYNCK();

    for (int c = 0; c < NCH; c += 3) {
        // ---- phase 0: chunk c on xb0 / wA --------------------------------
        if (c + 3 < NCH) LOADX(pfA, c + 3);
        LOADW(wC, c + 2);
        MFMA_CHUNK(xb0, wA);
        WRITEX(pfB, xb1);                 // chunk c+1 (loaded 3 phases ago)
        SYNCK();
        // ---- phase 1: chunk c+1 on xb1 / wB ------------------------------
        if (c + 3 < NCH) LOADW(wA, c + 3);
        if (c + 4 < NCH) LOADX(pfB, c + 4);
        MFMA_CHUNK(xb1, wB);
        WRITEX(pfC, xb2);                 // chunk c+2
        SYNCK();
        // ---- phase 2: chunk c+2 on xb2 / wC ------------------------------
        if (c + 4 < NCH) LOADW(wB, c + 4);
        if (c + 5 < NCH) LOADX(pfC, c + 5);
        MFMA_CHUNK(xb2, wC);
        if (c + 3 < NCH) WRITEX(pfA, xb0); // chunk c+3
        SYNCK();
    }
    __syncthreads();                      // single full drain before overlay

    // -------- logits(+bias) -> LDS [32][130] --------------------------------
    float* logitsL = (float*)smem;
    const float bv0 = bias[wv * 32 + r];
    const float bv1 = bias[wv * 32 + 16 + r];
#pragma unroll
    for (int q = 0; q < 4; ++q) {
        int m0 = g * 4 + q, m1 = m0 + 16;
        int e0 = wv * 32 + r, e1 = e0 + 16;
        logitsL[m0 * 130 + e0] = a00[q] + bv0;
        logitsL[m0 * 130 + e1] = a01[q] + bv1;
        logitsL[m1 * 130 + e0] = a10[q] + bv0;
        logitsL[m1 * 130 + e1] = a11[q] + bv1;
    }
    float*  cvf = (float*) (smem + 16640);   // [32][8]
    int*    cie = (int*)   (smem + 17664);   // [32][8]
    int*    flg = (int*)   (smem + 18688);   // [32]
    double* svd = (double*)(smem + 18816);   // [32][4]
    int*    sid = (int*)   (smem + 19840);   // [32][4]
    double* cvd = (double*)(smem + 20352);   // [8]
    __syncthreads();

    // -------- stripe top-8: thread (t, s) scans experts [s*16, s*16+16) -----
    {
        const int t = tid >> 3, s = tid & 7;
        float v[8]; int id[8];
#pragma unroll
        for (int k = 0; k < 8; ++k) { v[k] = -3.4e38f; id[k] = 0x7fffffff; }
        for (int jj = 0; jj < 16; ++jj) {
            float lv = logitsL[t * 130 + s * 16 + jj];
            int   e  = s * 16 + jj;
            bool gt[8];
#pragma unroll
            for (int k = 0; k < 8; ++k)
                gt[k] = (lv > v[k]) || (lv == v[k] && e < id[k]);
#pragma unroll
            for (int k = 7; k >= 1; --k)
                if (gt[k - 1]) { v[k] = v[k - 1]; id[k] = id[k - 1]; }
#pragma unroll
            for (int k = 0; k < 8; ++k) {
                bool put = gt[k] && (k == 0 || !gt[k - 1]);
                if (put) { v[k] = lv; id[k] = e; }
            }
        }
#pragma unroll
        for (int rd = 0; rd < 8; ++rd) {
            float hv = v[0]; int hi = id[0];
#pragma unroll
            for (int off = 1; off < 8; off <<= 1) {
                float ov = __shfl_xor(hv, off);
                int   oi = __shfl_xor(hi, off);
                if (ov > hv || (ov == hv && oi < hi)) { hv = ov; hi = oi; }
            }
            if (s == 0) { cvf[t * 8 + rd] = hv; cie[t * 8 + rd] = hi; }
            bool mine = (v[0] == hv) && (id[0] == hi);
            if (mine) {
#pragma unroll
                for (int k = 0; k < 7; ++k) { v[k] = v[k + 1]; id[k] = id[k + 1]; }
                v[7] = -3.4e38f; id[7] = 0x7fffffff;
            }
        }
    }
    __syncthreads();

    // -------- certified-gap test + fast-path fill ---------------------------
    if (tid < TM) {
        float gmin = 3.4e38f;
#pragma unroll
        for (int k = 0; k < 4; ++k)
            gmin = fminf(gmin, cvf[tid * 8 + k] - cvf[tid * 8 + k + 1]);
        flg[tid] = (gmin < TAU);
    }
    if (tid < 128) {
        int t2 = tid >> 2, k = tid & 3;
        svd[t2 * 4 + k] = (double)cvf[t2 * 8 + k];
        sid[t2 * 4 + k] = cie[t2 * 8 + k];
    }
    __syncthreads();

    // -------- rare slow path: fp64 rescore (2 candidates per wave) ----------
    for (int ts = 0; ts < TM; ++ts) {
        if (!flg[ts]) continue;              // uniform across block
#pragma unroll
        for (int h2 = 0; h2 < 2; ++h2) {
            const int cand = wv * 2 + h2;
            const int ce = cie[ts * 8 + cand];
            const float4* xr = (const float4*)(x + (size_t)(tok0 + ts) * HDIM);
            const float4* wr = (const float4*)(w + (size_t)ce * HDIM);
            double q0 = 0.0, q1 = 0.0, q2 = 0.0, q3 = 0.0;
            for (int i2 = 0; i2 < 12; ++i2) {
                int fi = lane + i2 * 64;
                if (fi < HDIM / 4) {
                    float4 xv = xr[fi];
                    float4 wv4 = wr[fi];
                    q0 = fma((double)xv.x, (double)wv4.x, q0);
                    q1 = fma((double)xv.y, (double)wv4.y, q1);
                    q2 = fma((double)xv.z, (double)wv4.z, q2);
                    q3 = fma((double)xv.w, (double)wv4.w, q3);
                }
            }
            double accd = (q0 + q2) + (q1 + q3);
#pragma unroll
            for (int off = 32; off > 0; off >>= 1)
                accd += __shfl_xor(accd, off);
            if (lane == 0) cvd[cand] = accd + (double)bias[ce];
        }
        __syncthreads();
        if (tid < 8) {                        // fp64 rank among 8 candidates
            double mv = cvd[tid]; int mi2 = cie[ts * 8 + tid];
            int rk = 0;
#pragma unroll
            for (int j2 = 0; j2 < 8; ++j2) {
                double oj = cvd[j2];
                rk += (oj > mv) || (oj == mv && cie[ts * 8 + j2] < mi2);
            }
            if (rk < 4) { svd[ts * 4 + rk] = mv; sid[ts * 4 + rk] = mi2; }
        }
        __syncthreads();
    }

    // -------- softmax + outputs ---------------------------------------------
    float* srow = (float*)smem;              // [32][128], overlays dead logits
    float4 z4 = make_float4(0.f, 0.f, 0.f, 0.f);
#pragma unroll
    for (int i = 0; i < 4; ++i)
        ((float4*)srow)[tid + i * NT] = z4;
    __syncthreads();

    if (tid < TM) {
        double m  = svd[tid * 4];
        double e0 = exp(svd[tid * 4 + 0] - m), e1 = exp(svd[tid * 4 + 1] - m);
        double e2 = exp(svd[tid * 4 + 2] - m), e3 = exp(svd[tid * 4 + 3] - m);
        double inv = 1.0 / ((e0 + e1) + (e2 + e3));
        float* oidx = out + (size_t)T_TOK * EEXP + (size_t)(tok0 + tid) * KTOP;
        int i0 = sid[tid * 4 + 0], i1 = sid[tid * 4 + 1];
        int i2 = sid[tid * 4 + 2], i3 = sid[tid * 4 + 3];
        oidx[0] = (float)i0; oidx[1] = (float)i1;
        oidx[2] = (float)i2; oidx[3] = (float)i3;
        srow[tid * EEXP + i0] = (float)(e0 * inv);
        srow[tid * EEXP + i1] = (float)(e1 * inv);
        srow[tid * EEXP + i2] = (float)(e2 * inv);
        srow[tid * EEXP + i3] = (float)(e3 * inv);
    }
    __syncthreads();

    float4* orow = (float4*)(out + (size_t)tok0 * EEXP);
#pragma unroll
    for (int i = 0; i < 4; ++i)
        orow[tid + i * NT] = ((float4*)srow)[tid + i * NT];
}

extern "C" void kernel_launch(void* const* d_in, const int* in_sizes, int n_in,
                              void* d_out, int out_size, void* d_ws, size_t ws_size,
                              hipStream_t stream) {
    const float* x    = (const float*)d_in[0];
    const float* w    = (const float*)d_in[1];
    const float* bias = (const float*)d_in[2];
    float* out        = (float*)d_out;
    char*  wp         = (char*)d_ws;   // 1440 KiB (8*45*2*2 tiles * 1KB)

    hipLaunchKernelGGL(w_split, dim3(180), dim3(256), 0, stream, w, wp);
    hipLaunchKernelGGL(router_fused, dim3(T_TOK / TM), dim3(NT), 0, stream,
                       x, wp, w, bias, out);
}